// Round 1
// 380.965 us; speedup vs baseline: 1.3054x; 1.3054x over previous
//
#include <hip/hip_runtime.h>
#include <math.h>

#define BN    8
#define NN    1024
#define HH    64
#define ADIM  8
#define STEPS 5
#define K2    2048                 // N*E
#define ROWS  (BN*NN)              // 8192

typedef __attribute__((ext_vector_type(8))) short bf16x8;
typedef __attribute__((ext_vector_type(4))) float f32x4;

__device__ __forceinline__ unsigned short f2bf(float f) {
    unsigned int u = __float_as_uint(f);
    u += 0x7FFF + ((u >> 16) & 1);          // round-to-nearest-even
    return (unsigned short)(u >> 16);
}
__device__ __forceinline__ float bf2f(unsigned short h) {
    return __uint_as_float(((unsigned int)h) << 16);
}

// ---------------- one-time: adjacency fp32 -> bf16 ----------------
__global__ __launch_bounds__(256) void conv_adj(
    const float* __restrict__ in, unsigned short* __restrict__ out)
{
    int tid = blockIdx.x * 256 + threadIdx.x;     // 0..2097151
    #pragma unroll
    for (int i = 0; i < 4; ++i) {
        size_t idx = (size_t)tid + (size_t)i * 2097152;
        float4 v = ((const float4*)in)[idx];
        ushort4 o;
        o.x = f2bf(v.x); o.y = f2bf(v.y); o.z = f2bf(v.z); o.w = f2bf(v.w);
        ((ushort4*)out)[idx] = o;
    }
}

// ---------------- one-time: Wg/We -> transposed bf16 hi/lo packs ----------
// wgp[s][c][k] : s in {hi,lo}, c = 0..63 (out col), k = 0..191  (from Wg[192][64])
// wep[s][c][k] : c = 0..127 (out col), k = 0..63                (from We[64][128])
__global__ __launch_bounds__(256) void prep_pack(
    const float* __restrict__ Wg, const float* __restrict__ We,
    unsigned short* __restrict__ wgp, unsigned short* __restrict__ wep)
{
    int t = blockIdx.x * 256 + threadIdx.x;
    if (t < 12288) {
        int k = t >> 6, c = t & 63;
        float v = Wg[t];
        unsigned short hi = f2bf(v);
        unsigned short lo = f2bf(v - bf2f(hi));
        wgp[(size_t)c * 192 + k] = hi;
        wgp[(size_t)(64 + c) * 192 + k] = lo;
    } else if (t < 20480) {
        int u = t - 12288;
        int k = u >> 7, c = u & 127;
        float v = We[u];
        unsigned short hi = f2bf(v);
        unsigned short lo = f2bf(v - bf2f(hi));
        wep[(size_t)c * 64 + k] = hi;
        wep[(size_t)(128 + c) * 64 + k] = lo;
    }
}

// ---------------- init: h_ws = initial_state; edge_t = f(initial_state) ----------
__global__ __launch_bounds__(256) void init_kernel(
    const float* __restrict__ init_state,
    const float* __restrict__ We, const float* __restrict__ be,
    float* __restrict__ h_ws, unsigned short* __restrict__ edge_t)
{
    __shared__ float h_lds[4][65];
    int t = threadIdx.x;
    int r = t >> 6, hp = t & 63;
    int row = blockIdx.x * 4 + r;
    float hv = init_state[(size_t)row * 64 + hp];
    h_ws[(size_t)row * 64 + hp] = hv;
    h_lds[r][hp] = hv;
    __syncthreads();
    int b = row >> 10, n = row & 1023;
    #pragma unroll
    for (int e = 0; e < 2; ++e) {
        float acc = be[hp * 2 + e];
        #pragma unroll 8
        for (int c = 0; c < 64; ++c)
            acc += h_lds[r][c] * We[c * 128 + hp * 2 + e];
        edge_t[((size_t)b * 64 + hp) * K2 + e * NN + n] = f2bf(acc);
    }
}

// ---------------- fused step: full-K GEMM + gate + edge, 32 rows/block ----------
// grid = 256 = 8 b x 32 row-tiles; 256 threads = 4 waves.
// GEMM waves: w = dir*2 + rh  -> 16 rows x 64 cols, K=2048 in 8 chunks (dbuf LDS B).
// gate/edge: MFMA with hi/lo bf16 split (fp32-equivalent to ~3e-5 rel).
__global__ __launch_bounds__(256) void step_kernel(
    const unsigned short* __restrict__ adjb,     // [b][n][4096] bf16
    const unsigned short* __restrict__ ein,      // [b][64][2048] bf16 (edge of h_s)
    unsigned short* __restrict__ eout,           // [b][64][2048] bf16 (edge of h_{s+1})
    float* __restrict__ h_ws,
    const unsigned short* __restrict__ wgp,      // [2][64][192]
    const unsigned short* __restrict__ wep,      // [2][128][64]
    const float* __restrict__ bg,
    const float* __restrict__ be,
    int do_edge)
{
    __shared__ __attribute__((aligned(16))) unsigned short Bs[2][64][264];  // 67.6 KB
    __shared__ __attribute__((aligned(16))) unsigned short Xhi[32][200];    // 12.8 KB
    __shared__ __attribute__((aligned(16))) unsigned short Xlo[32][200];    // 12.8 KB
    __shared__ __attribute__((aligned(16))) float          hf [32][68];     //  8.7 KB
    __shared__ __attribute__((aligned(16))) unsigned short HNhi[32][72];    //  4.6 KB
    __shared__ __attribute__((aligned(16))) unsigned short HNlo[32][72];    //  4.6 KB

    int t  = threadIdx.x;
    int b  = blockIdx.x >> 5;
    int mt = blockIdx.x & 31;
    int n0 = mt * 32;
    size_t hbase = ((size_t)(b * NN + n0)) * 64;

    // ---- load h rows -> X[.][128..191] (hi/lo) + hf ----
    {
        int r = t >> 3, cg = (t & 7) * 8;
        const float* hptr = h_ws + hbase + (size_t)r * 64 + cg;
        float4 v0 = *(const float4*)hptr;
        float4 v1 = *(const float4*)(hptr + 4);
        float vv[8] = {v0.x, v0.y, v0.z, v0.w, v1.x, v1.y, v1.z, v1.w};
        #pragma unroll
        for (int j = 0; j < 8; ++j) {
            float v = vv[j];
            unsigned short hi = f2bf(v), lo = f2bf(v - bf2f(hi));
            Xhi[r][128 + cg + j] = hi;
            Xlo[r][128 + cg + j] = lo;
            hf[r][cg + j] = v;
        }
    }

    int lane = t & 63, w = t >> 6, l15 = lane & 15, q = lane >> 4;
    int dir = w >> 1, rh = w & 1;

    const unsigned short* Abase = adjb
        + ((size_t)(b * NN + n0 + rh * 16 + l15)) * 4096 + dir * K2;

    // staging map (conflict-free: consecutive lanes -> consecutive 16B)
    int srow[8], scol[8];
    const unsigned short* sptr[8];
    #pragma unroll
    for (int i = 0; i < 8; ++i) {
        int u = i * 256 + t;
        srow[i] = u >> 5; scol[i] = (u & 31) * 8;
        sptr[i] = ein + ((size_t)b * 64 + srow[i]) * K2 + scol[i];
    }
    #pragma unroll
    for (int i = 0; i < 8; ++i)
        *(uint4*)&Bs[0][srow[i]][scol[i]] = *(const uint4*)(sptr[i]);
    __syncthreads();

    f32x4 acc[4];
    #pragma unroll
    for (int ct = 0; ct < 4; ++ct) acc[ct] = (f32x4){0.f, 0.f, 0.f, 0.f};

    bf16x8 af[8];
    #pragma unroll
    for (int ks = 0; ks < 8; ++ks)
        af[ks] = *(const bf16x8*)(Abase + ks * 32 + q * 8);

    #pragma unroll
    for (int c = 0; c < 8; ++c) {
        int buf = c & 1;
        uint4 g[8];
        bf16x8 afn[8];
        if (c < 7) {
            #pragma unroll
            for (int i = 0; i < 8; ++i)
                g[i] = *(const uint4*)(sptr[i] + (c + 1) * 256);
            #pragma unroll
            for (int ks = 0; ks < 8; ++ks)
                afn[ks] = *(const bf16x8*)(Abase + (c + 1) * 256 + ks * 32 + q * 8);
        }
        #pragma unroll
        for (int ks = 0; ks < 8; ++ks) {
            #pragma unroll
            for (int ct = 0; ct < 4; ++ct) {
                bf16x8 bfr = *(const bf16x8*)&Bs[buf][ct * 16 + l15][ks * 32 + q * 8];
                acc[ct] = __builtin_amdgcn_mfma_f32_16x16x32_bf16(af[ks], bfr, acc[ct], 0, 0, 0);
            }
        }
        if (c < 7) {
            #pragma unroll
            for (int i = 0; i < 8; ++i)
                *(uint4*)&Bs[buf ^ 1][srow[i]][scol[i]] = g[i];
            #pragma unroll
            for (int ks = 0; ks < 8; ++ks) af[ks] = afn[ks];
        }
        __syncthreads();
    }

    // ---- exchange: acc (a_in | a_out) -> X cols 0..127 as bf16 hi/lo ----
    #pragma unroll
    for (int ct = 0; ct < 4; ++ct) {
        #pragma unroll
        for (int i = 0; i < 4; ++i) {
            float v = acc[ct][i];
            unsigned short hi = f2bf(v), lo = f2bf(v - bf2f(hi));
            int r  = rh * 16 + q * 4 + i;
            int cc = dir * 64 + ct * 16 + l15;
            Xhi[r][cc] = hi;
            Xlo[r][cc] = lo;
        }
    }
    __syncthreads();

    // ---- gate (MFMA, hi/lo split): wave w -> m-tile (w&1), cols (w>>1)*32.. ----
    int mg = w & 1, ct0 = (w >> 1) * 2;
    int arow = mg * 16 + l15;
    f32x4 as[2], az[2];
    as[0] = as[1] = (f32x4){0.f, 0.f, 0.f, 0.f};

    #pragma unroll
    for (int ks = 0; ks < 4; ++ks) {                 // shared K = 0..127 (a_in|a_out)
        bf16x8 ah = *(const bf16x8*)&Xhi[arow][ks * 32 + q * 8];
        bf16x8 al = *(const bf16x8*)&Xlo[arow][ks * 32 + q * 8];
        #pragma unroll
        for (int p = 0; p < 2; ++p) {
            int cc = (ct0 + p) * 16 + l15;
            const unsigned short* wb = wgp + (size_t)cc * 192 + ks * 32 + q * 8;
            bf16x8 bh = *(const bf16x8*)wb;
            bf16x8 bl = *(const bf16x8*)(wb + 64 * 192);
            as[p] = __builtin_amdgcn_mfma_f32_16x16x32_bf16(ah, bh, as[p], 0, 0, 0);
            as[p] = __builtin_amdgcn_mfma_f32_16x16x32_bf16(ah, bl, as[p], 0, 0, 0);
            as[p] = __builtin_amdgcn_mfma_f32_16x16x32_bf16(al, bh, as[p], 0, 0, 0);
        }
    }
    az[0] = as[0]; az[1] = as[1];
    #pragma unroll
    for (int ks = 4; ks < 6; ++ks) {                 // z extra: K = 128..191 (h)
        bf16x8 ah = *(const bf16x8*)&Xhi[arow][ks * 32 + q * 8];
        bf16x8 al = *(const bf16x8*)&Xlo[arow][ks * 32 + q * 8];
        #pragma unroll
        for (int p = 0; p < 2; ++p) {
            int cc = (ct0 + p) * 16 + l15;
            const unsigned short* wb = wgp + (size_t)cc * 192 + ks * 32 + q * 8;
            bf16x8 bh = *(const bf16x8*)wb;
            bf16x8 bl = *(const bf16x8*)(wb + 64 * 192);
            az[p] = __builtin_amdgcn_mfma_f32_16x16x32_bf16(ah, bh, az[p], 0, 0, 0);
            az[p] = __builtin_amdgcn_mfma_f32_16x16x32_bf16(ah, bl, az[p], 0, 0, 0);
            az[p] = __builtin_amdgcn_mfma_f32_16x16x32_bf16(al, bh, az[p], 0, 0, 0);
        }
    }
    __syncthreads();   // all waves done reading h slots before zh overwrite

    float zv[2][4], hv[2][4];
    #pragma unroll
    for (int p = 0; p < 2; ++p) {
        int cc = (ct0 + p) * 16 + l15;
        float bgv = bg[cc];
        #pragma unroll
        for (int i = 0; i < 4; ++i) {
            int r = mg * 16 + q * 4 + i;
            float z = 1.f / (1.f + __expf(-(az[p][i] + bgv)));
            float h = hf[r][cc];
            zv[p][i] = z; hv[p][i] = h;
            float zh = z * h;
            unsigned short hi = f2bf(zh), lo = f2bf(zh - bf2f(hi));
            Xhi[r][128 + cc] = hi;
            Xlo[r][128 + cc] = lo;
        }
    }
    __syncthreads();

    #pragma unroll
    for (int ks = 4; ks < 6; ++ks) {                 // ht extra: K = 128..191 (zh)
        bf16x8 ah = *(const bf16x8*)&Xhi[arow][ks * 32 + q * 8];
        bf16x8 al = *(const bf16x8*)&Xlo[arow][ks * 32 + q * 8];
        #pragma unroll
        for (int p = 0; p < 2; ++p) {
            int cc = (ct0 + p) * 16 + l15;
            const unsigned short* wb = wgp + (size_t)cc * 192 + ks * 32 + q * 8;
            bf16x8 bh = *(const bf16x8*)wb;
            bf16x8 bl = *(const bf16x8*)(wb + 64 * 192);
            as[p] = __builtin_amdgcn_mfma_f32_16x16x32_bf16(ah, bh, as[p], 0, 0, 0);
            as[p] = __builtin_amdgcn_mfma_f32_16x16x32_bf16(ah, bl, as[p], 0, 0, 0);
            as[p] = __builtin_amdgcn_mfma_f32_16x16x32_bf16(al, bh, as[p], 0, 0, 0);
        }
    }

    #pragma unroll
    for (int p = 0; p < 2; ++p) {
        int cc = (ct0 + p) * 16 + l15;
        float bgv = bg[cc];
        #pragma unroll
        for (int i = 0; i < 4; ++i) {
            int r = mg * 16 + q * 4 + i;
            float ht = tanhf(as[p][i] + bgv);
            float z  = zv[p][i];
            float hn = (1.f - z) * hv[p][i] + z * ht;
            h_ws[hbase + (size_t)r * 64 + cc] = hn;
            if (do_edge) {
                unsigned short hi = f2bf(hn), lo = f2bf(hn - bf2f(hi));
                HNhi[r][cc] = hi;
                HNlo[r][cc] = lo;
            }
        }
    }
    if (!do_edge) return;
    __syncthreads();

    // ---- edge projection (MFMA, hi/lo split), transposed bf16 store ----
    int me = w & 1, cb = (w >> 1) * 4;
    int erow = me * 16 + l15;
    f32x4 ae[4];
    #pragma unroll
    for (int p = 0; p < 4; ++p) ae[p] = (f32x4){0.f, 0.f, 0.f, 0.f};
    #pragma unroll
    for (int ks = 0; ks < 2; ++ks) {
        bf16x8 ah = *(const bf16x8*)&HNhi[erow][ks * 32 + q * 8];
        bf16x8 al = *(const bf16x8*)&HNlo[erow][ks * 32 + q * 8];
        #pragma unroll
        for (int p = 0; p < 4; ++p) {
            int cc = (cb + p) * 16 + l15;
            const unsigned short* wb = wep + (size_t)cc * 64 + ks * 32 + q * 8;
            bf16x8 bh = *(const bf16x8*)wb;
            bf16x8 bl = *(const bf16x8*)(wb + 128 * 64);
            ae[p] = __builtin_amdgcn_mfma_f32_16x16x32_bf16(ah, bh, ae[p], 0, 0, 0);
            ae[p] = __builtin_amdgcn_mfma_f32_16x16x32_bf16(ah, bl, ae[p], 0, 0, 0);
            ae[p] = __builtin_amdgcn_mfma_f32_16x16x32_bf16(al, bh, ae[p], 0, 0, 0);
        }
    }
    #pragma unroll
    for (int p = 0; p < 4; ++p) {
        int cc = (cb + p) * 16 + l15;
        float bev = be[cc];
        int hp2 = cc >> 1, e = cc & 1;
        size_t ebase = ((size_t)b * 64 + hp2) * K2 + (size_t)e * NN
                     + n0 + me * 16 + q * 4;
        ushort4 ev;
        ev.x = f2bf(ae[p][0] + bev);
        ev.y = f2bf(ae[p][1] + bev);
        ev.z = f2bf(ae[p][2] + bev);
        ev.w = f2bf(ae[p][3] + bev);
        *(ushort4*)(eout + ebase) = ev;
    }
}

// ---------------- output head ----------
__global__ __launch_bounds__(256) void head_kernel(
    const float* __restrict__ h_ws, const float* __restrict__ ann,
    const float* __restrict__ Wh, const float* __restrict__ bh,
    const float* __restrict__ Wo, const float* __restrict__ bo,
    float* __restrict__ out)
{
    __shared__ float Wh_l[72 * 64];
    __shared__ float ha[4][72];
    int t = threadIdx.x;
    #pragma unroll
    for (int l = 0; l < 18; ++l) {
        int idx = t + l * 256;
        Wh_l[idx] = Wh[idx];
    }
    int r = t >> 6, hp = t & 63;
    int row = blockIdx.x * 4 + r;
    ha[r][hp] = h_ws[(size_t)row * 64 + hp];
    if (hp < ADIM) ha[r][64 + hp] = ann[(size_t)row * ADIM + hp];
    __syncthreads();

    float acc = bh[hp];
    #pragma unroll 8
    for (int k = 0; k < 72; ++k)
        acc += ha[r][k] * Wh_l[k * 64 + hp];
    float v = tanhf(acc) * Wo[hp];
    #pragma unroll
    for (int o = 32; o; o >>= 1) v += __shfl_down(v, o, 64);
    if (hp == 0) out[row] = v + bo[0];
}

extern "C" void kernel_launch(void* const* d_in, const int* in_sizes, int n_in,
                              void* d_out, int out_size, void* d_ws, size_t ws_size,
                              hipStream_t stream) {
    const float* init_state = (const float*)d_in[0];
    const float* ann = (const float*)d_in[1];
    const float* adj = (const float*)d_in[2];
    const float* We  = (const float*)d_in[3];
    const float* be  = (const float*)d_in[4];
    const float* Wg  = (const float*)d_in[5];
    const float* bg  = (const float*)d_in[6];
    const float* Wh  = (const float*)d_in[7];
    const float* bh  = (const float*)d_in[8];
    const float* Wo  = (const float*)d_in[9];
    const float* bo  = (const float*)d_in[10];
    float* out = (float*)d_out;

    // ws: adj_bf 64MB | edge_a 2MB | edge_b 2MB | h_ws 2MB | wgp 48KB | wep 32KB
    char* wsb = (char*)d_ws;
    unsigned short* adj_bf = (unsigned short*)wsb;
    unsigned short* edge_a = (unsigned short*)(wsb + 67108864);
    unsigned short* edge_b = (unsigned short*)(wsb + 69206016);
    float*          h_ws   = (float*)(wsb + 71303168);
    unsigned short* wgp    = (unsigned short*)(wsb + 73400320);
    unsigned short* wep    = (unsigned short*)(wsb + 73449472);

    conv_adj<<<dim3(8192), dim3(256), 0, stream>>>(adj, adj_bf);
    prep_pack<<<dim3(80), dim3(256), 0, stream>>>(Wg, We, wgp, wep);
    init_kernel<<<dim3(ROWS / 4), dim3(256), 0, stream>>>(init_state, We, be, h_ws, edge_a);
    for (int s = 0; s < STEPS; ++s) {
        const unsigned short* ein = (s & 1) ? edge_b : edge_a;
        unsigned short* eo        = (s & 1) ? edge_a : edge_b;
        step_kernel<<<dim3(256), dim3(256), 0, stream>>>(
            adj_bf, ein, eo, h_ws, wgp, wep, bg, be, (s < STEPS - 1) ? 1 : 0);
    }
    head_kernel<<<dim3(ROWS / 4), dim3(256), 0, stream>>>(h_ws, ann, Wh, bh, Wo, bo, out);
}